// Round 1
// 93.473 us; speedup vs baseline: 1.0195x; 1.0195x over previous
//
#include <hip/hip_runtime.h>
#include <hip/hip_bf16.h>

#define NUM_EMB 1024
#define EDIM 64
#define HW 4096      // 64*64 spatial
#define CHW 262144   // 64 ch * 4096
#define NPOS 65536   // 16 * 4096 positions
#define NOUT 4194304 // output elements (excl. loss scalar)

typedef __attribute__((ext_vector_type(8))) short short8;   // 8 bf16 = 4 VGPRs
typedef __attribute__((ext_vector_type(4))) float f32x4;

__device__ inline short f32_to_bf16_rne(float f) {
    unsigned u = __float_as_uint(f);
    unsigned r = (u + 0x7fffu + ((u >> 16) & 1u)) >> 16;
    return (short)r;
}

__device__ inline short f2bf(float f) {
    // hardware cvt (RNE); compiler pairs these into v_cvt_pk_bf16_f32
    return (short)__builtin_bit_cast(unsigned short, __float2bfloat16(f));
}

// Prep: codebook -> NEGATED bf16 swizzled B-fragments + biased half-norms.
// B-frag (16x16x32): lane=(n&15)|(quad<<4) holds -B[n][chunk*32+quad*8+j], j=0..7.
// Negation lets the main kernel fold the bias into the MFMA accumulator:
//   acc = h + sum((-e)*x) = h - e.x  (no per-score v_sub needed).
__global__ void vq_prep_kernel(const float* __restrict__ emb,
                               short* __restrict__ bsw,
                               float* __restrict__ hnb,
                               float* __restrict__ loss_out) {
    const int gid = blockIdx.x * 256 + threadIdx.x;   // 0..16383
    if (gid == 0) *loss_out = 0.0f;
    const int k  = gid >> 4;          // code id
    const int c0 = (gid & 15) * 4;    // channel group base
    float4 v = *(const float4*)(emb + k * EDIM + c0);
    float s = v.x * v.x + v.y * v.y + v.z * v.z + v.w * v.w;
#pragma unroll
    for (int m = 1; m < 16; m <<= 1) s += __shfl_xor(s, m, 64);
    if (c0 == 0) hnb[k] = 0.5f * s + 0.25f;           // bias -> scores positive

    const int T = k >> 4, nl = k & 15;
    const int chunk = c0 >> 5, quad = (c0 >> 3) & 3, j = c0 & 7;
    const int lane  = nl | (quad << 4);
    union { short s4[4]; uint2 u2; } pk;
    pk.s4[0] = f32_to_bf16_rne(-v.x);
    pk.s4[1] = f32_to_bf16_rne(-v.y);
    pk.s4[2] = f32_to_bf16_rne(-v.z);
    pk.s4[3] = f32_to_bf16_rne(-v.w);
    *(uint2*)(bsw + ((T * 2 + chunk) * 64 + lane) * 8 + j) = pk.u2;
}

// Main: block = 64 positions, 4 waves. ALL waves hold the same 64 positions
// (4 M-tiles of 16); wave w scans codebook quarter w (16 tiles of 16 codes).
// Phase 1 stages A cooperatively: wave w loads channels [16w,16w+16) for all
// 64 positions (coalesced 256B lines), converts bf16 once per element, and
// exchanges MFMA fragments through LDS (vs. old: each wave redundantly
// converted all 64 channels with strided scalar loads).
__global__ __launch_bounds__(256, 4) void vq_mfma_kernel(
        const float* __restrict__ inp,
        const float* __restrict__ emb,
        const short* __restrict__ bsw,
        const float* __restrict__ hnb,
        float* __restrict__ out,
        float* __restrict__ loss_out) {
    // [t*2+chunk][fraglane]; row length 65 -> 16B skew/row so the 4 t-groups
    // of a fragment write start on banks 0/8/16/24.
    __shared__ uint4    s_afrag[8][65];
    __shared__ float4   s_x4[16][64];     // [c>>2][pos] fp32 stash for epilogue
    __shared__ unsigned s_red[4][64];
    __shared__ int      s_idx[64];
    __shared__ float    s_wsum[4];

    const int tid  = threadIdx.x;
    const int w    = tid >> 6;        // wave id = codebook quarter = channel group
    const int lane = tid & 63;
    const int pb   = blockIdx.x * 64;
    const int b    = pb >> 12;
    const int hw0  = pb & 4095;

    // ---- Phase 1: cooperative A staging. lane = position, 16 channels/wave. --
    const float* xp = inp + (size_t)b * CHW + (w * 16) * HW + hw0 + lane;
    float x_[16];
#pragma unroll
    for (int i = 0; i < 16; ++i) x_[i] = xp[i * HW];   // 256B coalesced per i

#pragma unroll
    for (int g = 0; g < 4; ++g)                         // conflict-free: lanes
        s_x4[w * 4 + g][lane] =                         // contiguous within row
            make_float4(x_[4 * g], x_[4 * g + 1], x_[4 * g + 2], x_[4 * g + 3]);

    {
        // element (pos=lane, c=w*16+i) -> frag t=pos>>4, m=pos&15,
        // chunk=c>>5 (= w>>1), quad=(c>>3)&3, j=c&7, fraglane = m|(quad<<4)
        union { short s8[8]; uint4 u4; } lo_, hi_;
#pragma unroll
        for (int i = 0; i < 8; ++i) lo_.s8[i] = f2bf(x_[i]);
#pragma unroll
        for (int i = 0; i < 8; ++i) hi_.s8[i] = f2bf(x_[8 + i]);
        const int t = lane >> 4, m = lane & 15;
        const int chunk = w >> 1, qa = (2 * w) & 3;
        s_afrag[t * 2 + chunk][m | (qa << 4)]       = lo_.u4;
        s_afrag[t * 2 + chunk][m | ((qa + 1) << 4)] = hi_.u4;
    }
    __syncthreads();

    // ---- A fragments: contiguous lane*16B ds_read_b128, conflict-free ----
    short8 a[4][2];
#pragma unroll
    for (int t = 0; t < 4; ++t)
#pragma unroll
        for (int chunk = 0; chunk < 2; ++chunk)
            a[t][chunk] = __builtin_bit_cast(short8, s_afrag[t * 2 + chunk][lane]);

    unsigned best[4][4];
#pragma unroll
    for (int t = 0; t < 4; ++t)
#pragma unroll
        for (int r = 0; r < 4; ++r) best[t][r] = 0xFFFFFFFFu;

    // ---- k-loop: 16 tiles of 16 codes (this wave's quarter). acc starts at
    // h so MFMA output IS the biased score (B is negated). Packed-uint argmin:
    // u = (bits & ~0x3FF) | code_id  -> v_and_or_b32 + v_min_u32 per score. ----
    int kn = w * 256 + (lane & 15);
    const short* bp = bsw + (size_t)(w * 16) * 1024;
#pragma unroll 2
    for (int T = 0; T < 16; ++T) {
        const short8 b0 = *(const short8*)(bp + lane * 8);
        const short8 b1 = *(const short8*)(bp + 512 + lane * 8);
        const float  h  = hnb[kn];
        f32x4 acc[4];
#pragma unroll
        for (int t = 0; t < 4; ++t) acc[t] = (f32x4){h, h, h, h};
#pragma unroll
        for (int t = 0; t < 4; ++t) {
            acc[t] = __builtin_amdgcn_mfma_f32_16x16x32_bf16(a[t][0], b0, acc[t], 0, 0, 0);
            acc[t] = __builtin_amdgcn_mfma_f32_16x16x32_bf16(a[t][1], b1, acc[t], 0, 0, 0);
        }
#pragma unroll
        for (int t = 0; t < 4; ++t)
#pragma unroll
            for (int r = 0; r < 4; ++r) {
                unsigned u = (__float_as_uint(acc[t][r]) & ~1023u) | (unsigned)kn;
                if (u < best[t][r]) best[t][r] = u;
            }
        kn += 16;
        bp += 1024;
    }

    // ---- cross-lane min over the 16 codes (lanelo bits), stash per wave ----
#pragma unroll
    for (int t = 0; t < 4; ++t)
#pragma unroll
        for (int r = 0; r < 4; ++r) {
            unsigned bb = best[t][r];
#pragma unroll
            for (int m = 1; m < 16; m <<= 1) {
                unsigned o = __shfl_xor(bb, m, 64);
                if (o < bb) bb = o;
            }
            if ((lane & 15) == 0)
                s_red[w][t * 16 + (lane >> 4) * 4 + r] = bb;  // C/D row = quad*4+r
        }
    __syncthreads();

    if (tid < 64) {                                   // merge 4 codebook quarters
        unsigned u0 = s_red[0][tid], u1 = s_red[1][tid];
        unsigned u2 = s_red[2][tid], u3 = s_red[3][tid];
        unsigned m01 = u0 < u1 ? u0 : u1;
        unsigned m23 = u2 < u3 ? u2 : u3;
        s_idx[tid] = (int)((m01 < m23 ? m01 : m23) & 1023u);
    }
    __syncthreads();

    // ---- epilogue: gather exact fp32 code rows, write [B,C,H,W], loss.
    // Same (pos, channel-group) mapping as phase 1 -> x comes from s_x4. ----
    const int pos = lane;
    const int c0  = w * 16;
    const int myk = s_idx[pos];
    const float4* er4 = reinterpret_cast<const float4*>(emb + myk * EDIM + c0);
    float* orow = out + (size_t)b * CHW + hw0 + pos;
    float part = 0.0f;
#pragma unroll
    for (int g = 0; g < 4; ++g) {
        float4 q4 = er4[g];
        float4 xv = s_x4[w * 4 + g][pos];
        int c = c0 + g * 4;
        float d;
        d = q4.x - xv.x; part = fmaf(d, d, part); orow[(c + 0) * HW] = q4.x;
        d = q4.y - xv.y; part = fmaf(d, d, part); orow[(c + 1) * HW] = q4.y;
        d = q4.z - xv.z; part = fmaf(d, d, part); orow[(c + 2) * HW] = q4.z;
        d = q4.w - xv.w; part = fmaf(d, d, part); orow[(c + 3) * HW] = q4.w;
    }

#pragma unroll
    for (int off = 32; off > 0; off >>= 1)
        part += __shfl_down(part, off, 64);
    if (lane == 0) s_wsum[w] = part;
    __syncthreads();
    if (tid == 0) {
        float s = (s_wsum[0] + s_wsum[1]) + (s_wsum[2] + s_wsum[3]);
        atomicAdd(loss_out, s * (1.25f / (float)NOUT));
    }
}

extern "C" void kernel_launch(void* const* d_in, const int* in_sizes, int n_in,
                              void* d_out, int out_size, void* d_ws, size_t ws_size,
                              hipStream_t stream) {
    const float* inp = (const float*)d_in[0];    // [16,64,64,64] fp32
    const float* emb = (const float*)d_in[1];    // [1024,64] fp32
    float* out  = (float*)d_out;                 // 4194304 quantized + 1 loss
    float* loss = out + NOUT;

    short* bsw = (short*)d_ws;                           // 128 KiB bf16 swizzled -B
    float* hnb = (float*)((char*)d_ws + 131072);         // 4 KiB biased half-norms

    vq_prep_kernel<<<64, 256, 0, stream>>>(emb, bsw, hnb, loss);
    vq_mfma_kernel<<<NPOS / 64, 256, 0, stream>>>(inp, emb, bsw, hnb, out, loss);
}

// Round 2
// 90.621 us; speedup vs baseline: 1.0516x; 1.0315x over previous
//
#include <hip/hip_runtime.h>
#include <hip/hip_bf16.h>

#define NUM_EMB 1024
#define EDIM 64
#define HW 4096      // 64*64 spatial
#define CHW 262144   // 64 ch * 4096
#define NPOS 65536   // 16 * 4096 positions
#define NOUT 4194304 // output elements (excl. loss scalar)
#define POSB 128     // positions per block (8 M-tiles)

typedef __attribute__((ext_vector_type(8))) short short8;   // 8 bf16 = 4 VGPRs
typedef __attribute__((ext_vector_type(4))) float f32x4;

__device__ inline short f32_to_bf16_rne(float f) {
    unsigned u = __float_as_uint(f);
    unsigned r = (u + 0x7fffu + ((u >> 16) & 1u)) >> 16;
    return (short)r;
}

__device__ inline short f2bf(float f) {
    // hardware cvt (RNE); compiler pairs these into v_cvt_pk_bf16_f32
    return (short)__builtin_bit_cast(unsigned short, __float2bfloat16(f));
}

// Prep: codebook -> NEGATED bf16 swizzled B-fragments + biased half-norms.
// B-frag (16x16x32): lane=(n&15)|(quad<<4) holds -B[n][chunk*32+quad*8+j], j=0..7.
// Negation lets the main kernel fold the bias into the MFMA accumulator:
//   acc = h + sum((-e)*x) = h - e.x  (no per-score v_sub needed).
__global__ void vq_prep_kernel(const float* __restrict__ emb,
                               short* __restrict__ bsw,
                               float* __restrict__ hnb,
                               float* __restrict__ loss_out) {
    const int gid = blockIdx.x * 256 + threadIdx.x;   // 0..16383
    if (gid == 0) *loss_out = 0.0f;
    const int k  = gid >> 4;          // code id
    const int c0 = (gid & 15) * 4;    // channel group base
    float4 v = *(const float4*)(emb + k * EDIM + c0);
    float s = v.x * v.x + v.y * v.y + v.z * v.z + v.w * v.w;
#pragma unroll
    for (int m = 1; m < 16; m <<= 1) s += __shfl_xor(s, m, 64);
    if (c0 == 0) hnb[k] = 0.5f * s + 0.25f;           // bias -> scores positive

    const int T = k >> 4, nl = k & 15;
    const int chunk = c0 >> 5, quad = (c0 >> 3) & 3, j = c0 & 7;
    const int lane  = nl | (quad << 4);
    union { short s4[4]; uint2 u2; } pk;
    pk.s4[0] = f32_to_bf16_rne(-v.x);
    pk.s4[1] = f32_to_bf16_rne(-v.y);
    pk.s4[2] = f32_to_bf16_rne(-v.z);
    pk.s4[3] = f32_to_bf16_rne(-v.w);
    *(uint2*)(bsw + ((T * 2 + chunk) * 64 + lane) * 8 + j) = pk.u2;
}

// Main: block = 128 positions (8 M-tiles of 16), 4 waves. ALL waves hold the
// same 128 positions; wave w scans codebook quarter w (16 tiles of 16 codes).
// 128-position blocks halve per-block-amortized codebook traffic vs 64
// (134 MB -> 67 MB of bsw L1/L2 re-reads across the grid): the k-loop was
// TCP-port-bound (~70 B/cyc/CU demand vs ~64 peak), not HBM-bound.
__global__ __launch_bounds__(256, 2) void vq_mfma_kernel(
        const float* __restrict__ inp,
        const float* __restrict__ emb,
        const short* __restrict__ bsw,
        const float* __restrict__ hnb,
        float* __restrict__ out,
        float* __restrict__ loss_out) {
    // [t*2+chunk][fraglane]; row length 65 -> 16B skew/row so the 4 t-groups
    // of a fragment write start on banks 0/8/16/24.
    __shared__ uint4    s_afrag[16][65];
    __shared__ float4   s_x4[16][POSB];   // [c>>2][pos] fp32 stash for epilogue
    __shared__ unsigned s_red[4][POSB];
    __shared__ int      s_idx[POSB];
    __shared__ float    s_wsum[4];

    const int tid  = threadIdx.x;
    const int w    = tid >> 6;        // wave id = codebook quarter = channel group
    const int lane = tid & 63;
    const int pb   = blockIdx.x * POSB;
    const int b    = pb >> 12;        // POSB divides 4096 -> no image straddle
    const int hw0  = pb & 4095;

    // ---- Phase 1: cooperative A staging. wave w: channels [16w,16w+16) for
    // all 128 positions (two 64-position halves), coalesced 256B lines. ----
    const float* xp = inp + (size_t)b * CHW + (w * 16) * HW + hw0;
    float x_[2][16];
#pragma unroll
    for (int hlf = 0; hlf < 2; ++hlf)
#pragma unroll
        for (int i = 0; i < 16; ++i)
            x_[hlf][i] = xp[i * HW + hlf * 64 + lane];

#pragma unroll
    for (int hlf = 0; hlf < 2; ++hlf)
#pragma unroll
        for (int g = 0; g < 4; ++g)
            s_x4[w * 4 + g][hlf * 64 + lane] = make_float4(
                x_[hlf][4 * g], x_[hlf][4 * g + 1],
                x_[hlf][4 * g + 2], x_[hlf][4 * g + 3]);

    // element (pos, c=w*16+i) -> frag t=pos>>4, m=pos&15,
    // chunk=c>>5 (= w>>1), quad=(c>>3)&3 = qa+(i>>3), j=c&7=i&7,
    // fraglane = m|(quad<<4)
#pragma unroll
    for (int hlf = 0; hlf < 2; ++hlf) {
        union { short s8[8]; uint4 u4; } lo_, hi_;
#pragma unroll
        for (int i = 0; i < 8; ++i) lo_.s8[i] = f2bf(x_[hlf][i]);
#pragma unroll
        for (int i = 0; i < 8; ++i) hi_.s8[i] = f2bf(x_[hlf][8 + i]);
        const int t = hlf * 4 + (lane >> 4), m = lane & 15;
        const int chunk = w >> 1, qa = (2 * w) & 3;
        s_afrag[t * 2 + chunk][m | (qa << 4)]       = lo_.u4;
        s_afrag[t * 2 + chunk][m | ((qa + 1) << 4)] = hi_.u4;
    }
    __syncthreads();

    // ---- A fragments: contiguous lane*16B ds_read_b128, conflict-free ----
    short8 a[8][2];
#pragma unroll
    for (int t = 0; t < 8; ++t)
#pragma unroll
        for (int chunk = 0; chunk < 2; ++chunk)
            a[t][chunk] = __builtin_bit_cast(short8, s_afrag[t * 2 + chunk][lane]);

    unsigned best[8][4];
#pragma unroll
    for (int t = 0; t < 8; ++t)
#pragma unroll
        for (int r = 0; r < 4; ++r) best[t][r] = 0xFFFFFFFFu;

    // ---- k-loop: 16 tiles of 16 codes (this wave's quarter). C-operand hv
    // (D != C) starts every tile at h, so MFMA output IS the biased score
    // (B is negated). Packed-uint argmin: u = (bits & ~0x3FF) | code_id
    // -> v_and_or_b32 + v_min_u32 per score. ----
    int kn = w * 256 + (lane & 15);
    const short* bp = bsw + (size_t)(w * 16) * 1024;
#pragma unroll 2
    for (int T = 0; T < 16; ++T) {
        const short8 b0 = *(const short8*)(bp + lane * 8);
        const short8 b1 = *(const short8*)(bp + 512 + lane * 8);
        const float  h  = hnb[kn];
        const f32x4  hv = (f32x4){h, h, h, h};
        f32x4 acc[8];
#pragma unroll
        for (int t = 0; t < 8; ++t) {
            acc[t] = __builtin_amdgcn_mfma_f32_16x16x32_bf16(a[t][0], b0, hv, 0, 0, 0);
            acc[t] = __builtin_amdgcn_mfma_f32_16x16x32_bf16(a[t][1], b1, acc[t], 0, 0, 0);
        }
#pragma unroll
        for (int t = 0; t < 8; ++t)
#pragma unroll
            for (int r = 0; r < 4; ++r) {
                unsigned u = (__float_as_uint(acc[t][r]) & ~1023u) | (unsigned)kn;
                if (u < best[t][r]) best[t][r] = u;
            }
        kn += 16;
        bp += 1024;
    }

    // ---- cross-lane min over the 16 codes (lanelo bits), stash per wave ----
#pragma unroll
    for (int t = 0; t < 8; ++t)
#pragma unroll
        for (int r = 0; r < 4; ++r) {
            unsigned bb = best[t][r];
#pragma unroll
            for (int m = 1; m < 16; m <<= 1) {
                unsigned o = __shfl_xor(bb, m, 64);
                if (o < bb) bb = o;
            }
            if ((lane & 15) == 0)
                s_red[w][t * 16 + (lane >> 4) * 4 + r] = bb;  // C/D row = quad*4+r
        }
    __syncthreads();

    if (tid < POSB) {                                 // merge 4 codebook quarters
        unsigned u0 = s_red[0][tid], u1 = s_red[1][tid];
        unsigned u2 = s_red[2][tid], u3 = s_red[3][tid];
        unsigned m01 = u0 < u1 ? u0 : u1;
        unsigned m23 = u2 < u3 ? u2 : u3;
        s_idx[tid] = (int)((m01 < m23 ? m01 : m23) & 1023u);
    }
    __syncthreads();

    // ---- epilogue: gather exact fp32 code rows, write [B,C,H,W], loss.
    // Same (pos, channel-group) mapping as phase 1 -> x comes from s_x4. ----
    const int c0 = w * 16;
    float part = 0.0f;
#pragma unroll
    for (int hlf = 0; hlf < 2; ++hlf) {
        const int pos = hlf * 64 + lane;
        const int myk = s_idx[pos];
        const float4* er4 = reinterpret_cast<const float4*>(emb + myk * EDIM + c0);
        float* orow = out + (size_t)b * CHW + hw0 + pos;
#pragma unroll
        for (int g = 0; g < 4; ++g) {
            float4 q4 = er4[g];
            float4 xv = s_x4[w * 4 + g][pos];
            int c = c0 + g * 4;
            float d;
            d = q4.x - xv.x; part = fmaf(d, d, part); orow[(c + 0) * HW] = q4.x;
            d = q4.y - xv.y; part = fmaf(d, d, part); orow[(c + 1) * HW] = q4.y;
            d = q4.z - xv.z; part = fmaf(d, d, part); orow[(c + 2) * HW] = q4.z;
            d = q4.w - xv.w; part = fmaf(d, d, part); orow[(c + 3) * HW] = q4.w;
        }
    }

#pragma unroll
    for (int off = 32; off > 0; off >>= 1)
        part += __shfl_down(part, off, 64);
    if (lane == 0) s_wsum[w] = part;
    __syncthreads();
    if (tid == 0) {
        float s = (s_wsum[0] + s_wsum[1]) + (s_wsum[2] + s_wsum[3]);
        atomicAdd(loss_out, s * (1.25f / (float)NOUT));
    }
}

extern "C" void kernel_launch(void* const* d_in, const int* in_sizes, int n_in,
                              void* d_out, int out_size, void* d_ws, size_t ws_size,
                              hipStream_t stream) {
    const float* inp = (const float*)d_in[0];    // [16,64,64,64] fp32
    const float* emb = (const float*)d_in[1];    // [1024,64] fp32
    float* out  = (float*)d_out;                 // 4194304 quantized + 1 loss
    float* loss = out + NOUT;

    short* bsw = (short*)d_ws;                           // 128 KiB bf16 swizzled -B
    float* hnb = (float*)((char*)d_ws + 131072);         // 4 KiB biased half-norms

    vq_prep_kernel<<<64, 256, 0, stream>>>(emb, bsw, hnb, loss);
    vq_mfma_kernel<<<NPOS / POSB, 256, 0, stream>>>(inp, emb, bsw, hnb, out, loss);
}